// Round 1
// baseline (213.027 us; speedup 1.0000x reference)
//
#include <hip/hip_runtime.h>
#include <hip/hip_fp16.h>
#include <stdint.h>

// Problem constants (hardcoded per reference)
#define NROWS 131072   // B*L
#define DIM   256      // D
#define HDK   128      // H*DK
#define BM    16       // rows per workgroup
#define LDP   260      // padded f32 LDS row (256 + 4)
#define LDA   136      // padded half LDS row for V_att (128 + 8)

typedef _Float16 f16x8 __attribute__((ext_vector_type(8)));
typedef float    f32x4 __attribute__((ext_vector_type(4)));

// ---------------------------------------------------------------------------
// Pack W_q, W_k, W_v (256x128) and W_o (128x256) into fragment-linear fp16:
// for each (ntile, kstep), 64 lanes x 8 halves contiguous, so a B-fragment
// load is a single per-lane 16B load (1 KiB contiguous per wave).
// Layout: proj p at p*32768, frag index = ((nt*8 + ks)*64 + lane)*8 + j
//         W_o at 98304,      frag index = ((nt*4 + ks)*64 + lane)*8 + j
// ---------------------------------------------------------------------------
__global__ void pack_w(const float* __restrict__ Wq, const float* __restrict__ Wk,
                       const float* __restrict__ Wv, const float* __restrict__ Wo,
                       _Float16* __restrict__ wt) {
  int t = blockIdx.x * 256 + threadIdx.x;   // 0 .. 131071
  int seg = t >> 15;                        // 0..3
  int i = t & 32767;
  int j = i & 7;
  int l = (i >> 3) & 63;
  int rest = i >> 9;                        // nt*KS + ks
  const float* W;
  int N, k, n;
  if (seg < 3) {
    W = (seg == 0) ? Wq : ((seg == 1) ? Wk : Wv);
    N = HDK;
    int ks = rest & 7, nt = rest >> 3;
    k = ks * 32 + ((l >> 4) << 3) + j;      // 0..255
    n = nt * 16 + (l & 15);                 // 0..127
  } else {
    W = Wo;
    N = DIM;
    int ks = rest & 3, nt = rest >> 2;
    k = ks * 32 + ((l >> 4) << 3) + j;      // 0..127
    n = nt * 16 + (l & 15);                 // 0..255
  }
  wt[t] = (_Float16)W[k * N + n];
}

// ---------------------------------------------------------------------------
// Fused main kernel: stage 16 rows of Q,K,V (raw f32) in LDS; fp16 MFMA
// projections; per-head gated softmax fully in-register (16-lane groups);
// fp16 MFMA W_o; f32 final SiLU gate from raw staged Q,V.
// ---------------------------------------------------------------------------
__launch_bounds__(256, 3)
__global__ void uan_main(const float* __restrict__ Qg, const float* __restrict__ Kg,
                         const float* __restrict__ Vg, const _Float16* __restrict__ wt,
                         const float* __restrict__ Wl, const float* __restrict__ blv,
                         const float* __restrict__ Wsv, const float* __restrict__ bsv,
                         float* __restrict__ outg) {
  __shared__ __align__(16) float sQ[BM][LDP];
  __shared__ __align__(16) float sK[BM][LDP];
  __shared__ __align__(16) float sV[BM][LDP];
  __shared__ __align__(16) _Float16 sVA[BM][LDA];

  const int tid  = threadIdx.x;
  const int lane = tid & 63;
  const int wave = tid >> 6;        // 0..3
  const int c16  = lane & 15;       // col within 16-tile / head-dim index
  const int kg   = lane >> 4;       // k-group 0..3
  const size_t row0 = (size_t)blockIdx.x * BM;

  // ---- stage Q,K,V rows as raw f32 (coalesced float4) ----
#pragma unroll
  for (int it = 0; it < 12; ++it) {
    int chunk = tid + it * 256;               // 0..3071  (48 rows x 64 float4)
    int r  = chunk >> 6;                      // 0..47
    int c4 = (chunk & 63) << 2;               // f32 col
    int tsel = r >> 4;
    int rr   = r & 15;
    const float* src = (tsel == 0 ? Qg : (tsel == 1 ? Kg : Vg)) + (row0 + rr) * DIM + c4;
    float4 v = *(const float4*)src;
    float* dst = (tsel == 0 ? sQ[rr] : (tsel == 1 ? sK[rr] : sV[rr])) + c4;
    *(float4*)dst = v;
  }
  __syncthreads();

  // ---- projections: Qh,Kh,Vh via mfma_f32_16x16x32_f16 ----
  // wave w owns heads {2w, 2w+1} (N-tiles of 16 = one head each)
  f32x4 accP[3][2] = {};
  const float* sXp[3] = { &sQ[0][0], &sK[0][0], &sV[0][0] };
#pragma unroll
  for (int p = 0; p < 3; ++p) {
#pragma unroll
    for (int ks = 0; ks < 8; ++ks) {
      const float* ap = sXp[p] + c16 * LDP + ks * 32 + kg * 8;
      float4 a0 = *(const float4*)ap;
      float4 a1 = *(const float4*)(ap + 4);
      f16x8 af;
      af[0] = (_Float16)a0.x; af[1] = (_Float16)a0.y;
      af[2] = (_Float16)a0.z; af[3] = (_Float16)a0.w;
      af[4] = (_Float16)a1.x; af[5] = (_Float16)a1.y;
      af[6] = (_Float16)a1.z; af[7] = (_Float16)a1.w;
#pragma unroll
      for (int nt = 0; nt < 2; ++nt) {
        const f16x8 bf = *(const f16x8*)(wt + p * 32768 +
                          (size_t)(((wave * 2 + nt) * 8 + ks) * 64 + lane) * 8);
        accP[p][nt] = __builtin_amdgcn_mfma_f32_16x16x32_f16(af, bf, accP[p][nt], 0, 0, 0);
      }
    }
  }

  // ---- per-head gated softmax, in-register ----
  // C-fragment: value q of tile nt is row (kg*4+q), col c16 of head (wave*2+nt).
  // Each 16-lane group holds one full (row, head) vector -> shfl_xor reductions.
  const float wl0 = Wl[c16], wl1 = Wl[16 + c16], wsc = Wsv[c16];
  const float bl0 = blv[0], bl1 = blv[1], bs0 = bsv[0];

#pragma unroll
  for (int nt = 0; nt < 2; ++nt) {
    const int head = wave * 2 + nt;
#pragma unroll
    for (int q = 0; q < 4; ++q) {
      float qh = accP[0][nt][q];
      float kh = accP[1][nt][q];
      float vh = accP[2][nt][q];
      float left  = kh * qh;
      float right = vh * qh;
      float d0 = left * wl0;
      float d1 = left * wl1;
#pragma unroll
      for (int m = 1; m < 16; m <<= 1) {
        d0 += __shfl_xor(d0, m, 16);
        d1 += __shfl_xor(d1, m, 16);
      }
      float m0 = 1.0f / (1.0f + __expf(-(d0 + bl0)));
      float m1 = 1.0f / (1.0f + __expf(-(d1 + bl1)));
      float fix = left * m0 * m1;          // |fix| <~ 36 -> exp safe without max-sub
      float e   = __expf(fix);
      float num = e * wsc;
      float den = e;
#pragma unroll
      for (int m = 1; m < 16; m <<= 1) {
        num += __shfl_xor(num, m, 16);
        den += __shfl_xor(den, m, 16);
      }
      float score = num / den + bs0;
      float va = score * right;
      int row = kg * 4 + q;
      sVA[row][head * 16 + c16] = (_Float16)va;
    }
  }
  __syncthreads();

  // ---- W_o GEMM: (BM x 128) @ (128 x 256); wave w owns out cols [64w, 64w+64) ----
  f32x4 accO[4] = {};
#pragma unroll
  for (int ks = 0; ks < 4; ++ks) {
    const f16x8 af = *(const f16x8*)(&sVA[c16][ks * 32 + kg * 8]);
#pragma unroll
    for (int nt = 0; nt < 4; ++nt) {
      int nto = wave * 4 + nt;
      const f16x8 bf = *(const f16x8*)(wt + 98304 +
                        (size_t)((nto * 4 + ks) * 64 + lane) * 8);
      accO[nt] = __builtin_amdgcn_mfma_f32_16x16x32_f16(af, bf, accO[nt], 0, 0, 0);
    }
  }

  // ---- final: out = silu((V*Q) * V_att_out), all f32 from raw staged Q,V ----
#pragma unroll
  for (int nt = 0; nt < 4; ++nt) {
    const int col = wave * 64 + nt * 16 + c16;
#pragma unroll
    for (int q = 0; q < 4; ++q) {
      const int row = kg * 4 + q;
      float vq  = sV[row][col] * sQ[row][col];
      float att = vq * accO[nt][q];
      float o   = att / (1.0f + __expf(-att));
      outg[(row0 + row) * DIM + col] = o;
    }
  }
}

// ---------------------------------------------------------------------------
extern "C" void kernel_launch(void* const* d_in, const int* in_sizes, int n_in,
                              void* d_out, int out_size, void* d_ws, size_t ws_size,
                              hipStream_t stream) {
  const float* Q  = (const float*)d_in[0];
  const float* K  = (const float*)d_in[1];
  const float* V  = (const float*)d_in[2];
  const float* Wq = (const float*)d_in[3];
  const float* Wk = (const float*)d_in[4];
  const float* Wv = (const float*)d_in[5];
  const float* Wo = (const float*)d_in[6];
  const float* Wl = (const float*)d_in[7];
  const float* bl = (const float*)d_in[8];
  const float* Ws = (const float*)d_in[9];
  const float* bs = (const float*)d_in[10];
  _Float16* wt = (_Float16*)d_ws;   // 131072 halves = 256 KB of scratch
  float* out = (float*)d_out;

  pack_w<<<512, 256, 0, stream>>>(Wq, Wk, Wv, Wo, wt);
  uan_main<<<NROWS / BM, 256, 0, stream>>>(Q, K, V, wt, Wl, bl, Ws, bs, out);
}